// Round 4
// baseline (1740.564 us; speedup 1.0000x reference)
//
#include <hip/hip_runtime.h>
#include <hip/hip_bf16.h>
#include <hip/hip_fp16.h>

// Problem constants
#define N_PTS_IN   20000
#define CAP0C      540000
#define CAP1C      352000
#define ZD 10
#define YD 200
#define XD 704
#define Z1D 5
#define Y1D 100
#define X1D 352
#define HWOUT (YD*XD)   // 140800

typedef _Float16 f16x8 __attribute__((ext_vector_type(8)));
typedef float    f32x4 __attribute__((ext_vector_type(4)));

// ---------------------------------------------------------------------------
// f_in = sp_feats @ w_in   (20000x64 @ 64x32), f16 output rows
__global__ __launch_bounds__(256) void gemm_in(const float* __restrict__ sp,
                                               const float* __restrict__ w,
                                               __half* __restrict__ fout) {
    int tid = blockIdx.x * 256 + threadIdx.x;
    int row = tid >> 3;
    int c4  = (tid & 7) * 4;
    if (row >= N_PTS_IN) return;
    float4 acc = {0.f, 0.f, 0.f, 0.f};
    const float* sr = sp + (size_t)row * 64;
#pragma unroll
    for (int ci = 0; ci < 64; ci += 4) {
        float4 fv = *(const float4*)(sr + ci);
        const float* wp = w + ci * 32 + c4;
        float4 w0 = *(const float4*)(wp);
        float4 w1 = *(const float4*)(wp + 32);
        float4 w2 = *(const float4*)(wp + 64);
        float4 w3 = *(const float4*)(wp + 96);
        acc.x += fv.x*w0.x + fv.y*w1.x + fv.z*w2.x + fv.w*w3.x;
        acc.y += fv.x*w0.y + fv.y*w1.y + fv.z*w2.y + fv.w*w3.y;
        acc.z += fv.x*w0.z + fv.y*w1.z + fv.z*w2.z + fv.w*w3.z;
        acc.w += fv.x*w0.w + fv.y*w1.w + fv.z*w2.w + fv.w*w3.w;
    }
    __half* fo = fout + (size_t)row * 32 + c4;
    fo[0] = __float2half(acc.x);
    fo[1] = __float2half(acc.y);
    fo[2] = __float2half(acc.z);
    fo[3] = __float2half(acc.w);
}

// ---------------------------------------------------------------------------
// Weight convert+transpose: src f32 [27][CIN][COUT] -> dst f16 [27][COUT][CIN]
__global__ __launch_bounds__(256) void cvt_w(const float* __restrict__ src,
                                             __half* __restrict__ dst,
                                             int CIN, int COUT) {
    int i = blockIdx.x * 256 + threadIdx.x;
    if (i >= 27 * CIN * COUT) return;
    int ci = i % CIN;
    int t  = i / CIN;
    int co = t % COUT;
    int k  = t / COUT;
    dst[i] = __float2half(src[((size_t)k * CIN + ci) * COUT + co]);
}

// ct0_w f32 [320][64] (ci=c*10+z) -> f16 [co][zc=z*32+c]
__global__ __launch_bounds__(256) void cvt_ct0(const float* __restrict__ src,
                                               __half* __restrict__ dst) {
    int i = blockIdx.x * 256 + threadIdx.x;
    if (i >= 64 * 320) return;
    int zc = i % 320, co = i / 320;
    int z = zc >> 5, c = zc & 31;
    dst[i] = __float2half(src[(c * 10 + z) * 64 + co]);
}

// ct1_w f32 [320][64][2][2] (ci=c*5+z) -> f16 [kq][co][zc=z*64+c]
__global__ __launch_bounds__(256) void cvt_ct1(const float* __restrict__ src,
                                               __half* __restrict__ dst) {
    int i = blockIdx.x * 256 + threadIdx.x;
    if (i >= 4 * 64 * 320) return;
    int zc = i % 320;
    int t  = i / 320;
    int co = t & 63;
    int kq = t >> 6;
    int z = zc >> 6, c = zc & 63;
    dst[i] = __float2half(src[((c * 5 + z) * 64 + co) * 4 + kq]);
}

// ---------------------------------------------------------------------------
// Rulebook inversion, TRANSPOSED: nbrT[k*cap + s] = g
__global__ __launch_bounds__(256) void build_nbr(const int* __restrict__ g,
                                                 const int* __restrict__ s,
                                                 int* __restrict__ nbrT,
                                                 int P, int cap) {
    int i = blockIdx.x * 256 + threadIdx.x;
    if (i >= 27 * P) return;
    int k = i / P, p = i - k * P;
    int sv = s[(size_t)k * P + p];
    if (sv >= cap) return;              // dummy pair
    nbrT[(size_t)k * cap + sv] = g[(size_t)k * P + p];
}

// voxel -> sparse-row index (pad coords have z == Zdim, dropped like JAX OOB)
__global__ __launch_bounds__(256) void build_vox(const int* __restrict__ coords,
                                                 int* __restrict__ v2r,
                                                 int cap, int Zdim, int Ydim, int Xdim) {
    int r = blockIdx.x * 256 + threadIdx.x;
    if (r >= cap) return;
    int b = coords[4*r], z = coords[4*r+1], y = coords[4*r+2], x = coords[4*r+3];
    if (z >= Zdim) return;
    v2r[(((size_t)b * Zdim + z) * Ydim + y) * Xdim + x] = r;
}

// ---------------------------------------------------------------------------
// Implicit-GEMM sparse conv via f16 MFMA 16x16x32, + BN + ReLU.
// v10: direct-to-register gather, NO LDS in the main loop.
// R3 post-mortem arithmetic: per-k latency ~4800cy in ALL prior versions;
// duration differences were purely wave concurrency. Two root causes fixed:
//   (1) AGPRs (invisible in VGPR_Count) : f32x16 acc = 64 AGPR capped
//       occupancy at 3 waves/SIMD. Back to 16x16x32 / f32x4 acc (32 AGPR).
//   (2) in-order vmcnt: MFMA consumed the NEWEST loads -> every iteration
//       drained vmcnt(0), serializing the index prefetch (HBM ~900cy).
//       Now: gathers -> weights -> THEN k+2 index issue -> MFMA waits
//       vmcnt(2), leaving the index stream in flight. Depth-2 index
//       pipeline means the ballot consumes an index OLDER than the previous
//       MFMA's operands: zero stall.
// The 16B A-fragment of lane (quad,l16) is loaded straight from the gathered
// row (per-lane predicated load, exec-masked): the whole LDS stage/ds_write/
// ds_read round-trip is gone. LDS only for the epilogue store staging.
template <int CIN, int COUT>
__global__ __launch_bounds__(256) void spconv_reg(const __half* __restrict__ f,
                                                  const __half* __restrict__ wt,
                                                  const float* __restrict__ bnp,
                                                  const int* __restrict__ nbrT,
                                                  __half* __restrict__ fout,
                                                  int ncap) {
    constexpr int NT = COUT / 16;      // 16-col output tiles
    constexpr int KT = CIN / 32;       // K=32 MFMA steps per k-offset
    __shared__ __align__(16) __half Ost[4][32 * COUT];

    int tid = threadIdx.x;
    int wv = tid >> 6, lane = tid & 63;
    int quad = lane >> 4, l16 = lane & 15;

    // bijective XCD-aware block swizzle (m204 form)
    int nwg = gridDim.x;
    int q = nwg >> 3, rm = nwg & 7;
    int xcd = blockIdx.x & 7, off = blockIdx.x >> 3;
    int sb = (xcd < rm ? xcd * (q + 1) : rm * (q + 1) + (xcd - rm) * q) + off;

    int m0 = sb * 128 + wv * 32;       // wave's first output row
    int r0 = m0 + l16;                 // this lane's row for m=0
    int r1 = m0 + 16 + l16;            // this lane's row for m=1
    bool ok0 = r0 < ncap, ok1 = r1 < ncap;

    f32x4 acc[2][NT] = {};

    // index pipeline depth 2: ballot consumes 2-iteration-old loads
    int gC0 = ok0 ? nbrT[r0] : -1;
    int gC1 = ok1 ? nbrT[r1] : -1;
    int gN0 = ok0 ? nbrT[(size_t)ncap + r0] : -1;
    int gN1 = ok1 ? nbrT[(size_t)ncap + r1] : -1;
    bool ever = false;

#pragma unroll 1
    for (int k = 0; k < 27; ++k) {
        bool anyC = __ballot((gC0 >= 0) || (gC1 >= 0)) != 0ull;
        f16x8 a0[KT], a1[KT];
        f16x8 bfr[KT][NT];
        if (anyC) {
            // A fragments: per-lane 16B chunks of the two gathered rows
            const __half* p0 = f + (size_t)((gC0 < 0) ? 0 : gC0) * CIN + quad * 8;
            const __half* p1 = f + (size_t)((gC1 < 0) ? 0 : gC1) * CIN + quad * 8;
#pragma unroll
            for (int kt = 0; kt < KT; ++kt) {
                uint4 u0 = {0u,0u,0u,0u}, u1 = {0u,0u,0u,0u};
                if (gC0 >= 0) u0 = *(const uint4*)(p0 + kt * 32);
                if (gC1 >= 0) u1 = *(const uint4*)(p1 + kt * 32);
                a0[kt] = *(f16x8*)&u0;
                a1[kt] = *(f16x8*)&u1;
            }
            // B fragments (L2-hot weights), issued after gathers
            const __half* wk = wt + (size_t)k * (COUT * CIN) + (size_t)l16 * CIN + quad * 8;
#pragma unroll
            for (int kt = 0; kt < KT; ++kt)
#pragma unroll
                for (int nt = 0; nt < NT; ++nt)
                    bfr[kt][nt] = *(const f16x8*)(wk + nt * 16 * CIN + kt * 32);
        }
        // issue k+2 index loads LAST: the MFMA wait (vmcnt(2)) leaves them
        // in flight across the compute section
        int gNN0 = -1, gNN1 = -1;
        if (k + 2 < 27) {
            if (ok0) gNN0 = nbrT[(size_t)(k + 2) * ncap + r0];
            if (ok1) gNN1 = nbrT[(size_t)(k + 2) * ncap + r1];
        }
        if (anyC) {
            ever = true;
#pragma unroll
            for (int kt = 0; kt < KT; ++kt)
#pragma unroll
                for (int nt = 0; nt < NT; ++nt) {
                    acc[0][nt] = __builtin_amdgcn_mfma_f32_16x16x32_f16(a0[kt], bfr[kt][nt], acc[0][nt], 0, 0, 0);
                    acc[1][nt] = __builtin_amdgcn_mfma_f32_16x16x32_f16(a1[kt], bfr[kt][nt], acc[1][nt], 0, 0, 0);
                }
        }
        gC0 = gN0; gC1 = gN1; gN0 = gNN0; gN1 = gNN1;
    }

    // epilogue: BN + ReLU -> wave-private LDS -> coalesced store.
    // Waves that never saw a pair own rows >= n_act: never read downstream.
    if (!ever) return;
    __half* O = Ost[wv];
#pragma unroll
    for (int nt = 0; nt < NT; ++nt) {
        int co = nt * 16 + l16;
        float g = bnp[co], b = bnp[COUT + co];
        float mn = bnp[2*COUT + co], vv = bnp[3*COUT + co];
        float s  = g * rsqrtf(vv + 1e-5f);
        float sh = b - mn * s;
#pragma unroll
        for (int m = 0; m < 2; ++m)
#pragma unroll
            for (int r_ = 0; r_ < 4; ++r_) {
                int row = m * 16 + quad * 4 + r_;
                O[row * COUT + co] = __float2half(fmaxf(acc[m][nt][r_] * s + sh, 0.f));
            }
    }
    constexpr int OCH = COUT / 8;              // 16B chunks per out row
#pragma unroll
    for (int j = 0; j < 32 * OCH / 64; ++j) {
        int idx = j * 64 + lane;
        int r = idx / OCH, c = idx % OCH;
        if (m0 + r < ncap)
            *(uint4*)(fout + (size_t)(m0 + r) * COUT + c * 8) =
                *(const uint4*)(O + r * COUT + c * 8);
    }
}

// ---------------------------------------------------------------------------
// BEV head 0: fused gather + GEMM [64rows x 320] @ [320 x 64] via f16 MFMA,
// + BN + ReLU + 2-agent attention + coalesced store.
__global__ __launch_bounds__(256) void bev0_mfma(const __half* __restrict__ f0,
                                                 const __half* __restrict__ wtT,  // [64][320] zc=z*32+c
                                                 const float* __restrict__ bias,
                                                 const float* __restrict__ bnp,
                                                 const int* __restrict__ v2r,
                                                 float* __restrict__ out) {
    constexpr int AST = 328;
    __shared__ __align__(16) __half Al[64 * AST];   // 41,984 B
    __shared__ float Cl[64][65];                     // wave-private rows
    __shared__ float Ot[64][33];
    int tid = threadIdx.x;
    int y = blockIdx.x / 22, x0 = (blockIdx.x % 22) * 32;
    int wv = tid >> 6, lane = tid & 63;
    int quad = lane >> 4, l16 = lane & 15;

    for (int it = 0; it < 3; ++it) {
        int task = it * 256 + tid;
        if (task < 640) {
            int row = task & 63, z = task >> 6;
            int b = row & 1, p = row >> 1;
            int r = v2r[((b * ZD + z) * YD + y) * XD + x0 + p];
            uint4 v0 = {0,0,0,0}, v1 = {0,0,0,0}, v2 = {0,0,0,0}, v3 = {0,0,0,0};
            if (r >= 0) {
                const uint4* src = (const uint4*)(f0 + (size_t)r * 32);
                v0 = src[0]; v1 = src[1]; v2 = src[2]; v3 = src[3];
            }
            uint4* dst = (uint4*)(Al + row * AST + z * 32);
            dst[0] = v0; dst[1] = v1; dst[2] = v2; dst[3] = v3;
        }
    }
    __syncthreads();

    f32x4 acc[4] = {};
#pragma unroll
    for (int ks = 0; ks < 10; ++ks) {
        f16x8 a = *(const f16x8*)(Al + (wv * 16 + l16) * AST + ks * 32 + quad * 8);
#pragma unroll
        for (int nt = 0; nt < 4; ++nt) {
            f16x8 bfr = *(const f16x8*)(wtT + (size_t)(nt * 16 + l16) * 320 + ks * 32 + quad * 8);
            acc[nt] = __builtin_amdgcn_mfma_f32_16x16x32_f16(a, bfr, acc[nt], 0, 0, 0);
        }
    }
#pragma unroll
    for (int nt = 0; nt < 4; ++nt) {
        int co = nt * 16 + l16;
        float s  = bnp[co] * rsqrtf(bnp[192 + co] + 1e-5f);
        float sh = (bias[co] - bnp[128 + co]) * s + bnp[64 + co];
#pragma unroll
        for (int r_ = 0; r_ < 4; ++r_)
            Cl[wv * 16 + quad * 4 + r_][co] = fmaxf(acc[nt][r_] * s + sh, 0.f);
    }
#pragma unroll
    for (int pi = 0; pi < 8; ++pi) {
        int p = wv * 8 + pi;
        float x0v = Cl[2 * p][lane], x1v = Cl[2 * p + 1][lane];
        float s00 = x0v * x0v, s01 = x0v * x1v;
#pragma unroll
        for (int o = 32; o > 0; o >>= 1) {
            s00 += __shfl_xor(s00, o);
            s01 += __shfl_xor(s01, o);
        }
        float a0 = s00 * 0.125f, a1 = s01 * 0.125f;
        float mx = fmaxf(a0, a1);
        float e0 = expf(a0 - mx), e1 = expf(a1 - mx);
        float inv = 1.f / (e0 + e1);
        Ot[lane][p] = (e0 * x0v + e1 * x1v) * inv;
    }
    __syncthreads();
#pragma unroll
    for (int i = 0; i < 8; ++i) {
        int idx = i * 256 + tid;
        int co = idx >> 5, px = idx & 31;
        out[(size_t)co * HWOUT + (size_t)y * XD + x0 + px] = Ot[co][px];
    }
}

// ---------------------------------------------------------------------------
// BEV head 1: fused gather + 4x (GEMM [64x320]@[320x64]) for the 2x2 s2 convT
// kernel positions + BN + ReLU + attention + coalesced store.
__global__ __launch_bounds__(256) void bev1_mfma(const __half* __restrict__ f1,
                                                 const __half* __restrict__ wtT,  // [4][64][320] zc=z*64+c
                                                 const float* __restrict__ bias,
                                                 const float* __restrict__ bnp,
                                                 const int* __restrict__ v2r,
                                                 float* __restrict__ out) {
    constexpr int AST = 328;
    __shared__ __align__(16) __half Al[64 * AST];
    __shared__ float Cl[64][65];
    __shared__ float Ot[64][65];
    int tid = threadIdx.x;
    int iy = blockIdx.x / 11, j0 = (blockIdx.x % 11) * 32;
    int wv = tid >> 6, lane = tid & 63;
    int quad = lane >> 4, l16 = lane & 15;

    for (int it = 0; it < 3; ++it) {
        int task = it * 256 + tid;
        if (task < 640) {
            int row = task & 63, zh = task >> 6;   // 0..9
            int z = zh >> 1, hf = zh & 1;
            int b = row & 1, p = row >> 1;
            int r = v2r[((b * Z1D + z) * Y1D + iy) * X1D + j0 + p];
            uint4 v0 = {0,0,0,0}, v1 = {0,0,0,0}, v2 = {0,0,0,0}, v3 = {0,0,0,0};
            if (r >= 0) {
                const uint4* src = (const uint4*)(f1 + (size_t)r * 64 + hf * 32);
                v0 = src[0]; v1 = src[1]; v2 = src[2]; v3 = src[3];
            }
            uint4* dst = (uint4*)(Al + row * AST + z * 64 + hf * 32);
            dst[0] = v0; dst[1] = v1; dst[2] = v2; dst[3] = v3;
        }
    }
    __syncthreads();

#pragma unroll 1
    for (int ky = 0; ky < 2; ++ky) {
#pragma unroll 1
        for (int kx = 0; kx < 2; ++kx) {
            const __half* wk = wtT + (size_t)(ky * 2 + kx) * 64 * 320;
            f32x4 acc[4] = {};
#pragma unroll
            for (int ks = 0; ks < 10; ++ks) {
                f16x8 a = *(const f16x8*)(Al + (wv * 16 + l16) * AST + ks * 32 + quad * 8);
#pragma unroll
                for (int nt = 0; nt < 4; ++nt) {
                    f16x8 bfr = *(const f16x8*)(wk + (size_t)(nt * 16 + l16) * 320 + ks * 32 + quad * 8);
                    acc[nt] = __builtin_amdgcn_mfma_f32_16x16x32_f16(a, bfr, acc[nt], 0, 0, 0);
                }
            }
#pragma unroll
            for (int nt = 0; nt < 4; ++nt) {
                int co = nt * 16 + l16;
                float s  = bnp[co] * rsqrtf(bnp[192 + co] + 1e-5f);
                float sh = (bias[co] - bnp[128 + co]) * s + bnp[64 + co];
#pragma unroll
                for (int r_ = 0; r_ < 4; ++r_)
                    Cl[wv * 16 + quad * 4 + r_][co] = fmaxf(acc[nt][r_] * s + sh, 0.f);
            }
#pragma unroll
            for (int pi = 0; pi < 8; ++pi) {
                int p = wv * 8 + pi;
                float x0v = Cl[2 * p][lane], x1v = Cl[2 * p + 1][lane];
                float s00 = x0v * x0v, s01 = x0v * x1v;
#pragma unroll
                for (int o = 32; o > 0; o >>= 1) {
                    s00 += __shfl_xor(s00, o);
                    s01 += __shfl_xor(s01, o);
                }
                float a0 = s00 * 0.125f, a1 = s01 * 0.125f;
                float mx = fmaxf(a0, a1);
                float e0 = expf(a0 - mx), e1 = expf(a1 - mx);
                float inv = 1.f / (e0 + e1);
                Ot[lane][2 * p + kx] = (e0 * x0v + e1 * x1v) * inv;
            }
        }
        __syncthreads();
        int yo = 2 * iy + ky;
#pragma unroll
        for (int i = 0; i < 16; ++i) {
            int idx = i * 256 + tid;
            int co = idx >> 6, xx = idx & 63;
            out[(size_t)co * HWOUT + (size_t)yo * XD + 2 * j0 + xx] = Ot[co][xx];
        }
        __syncthreads();
    }
}

// ---------------------------------------------------------------------------
extern "C" void kernel_launch(void* const* d_in, const int* in_sizes, int n_in,
                              void* d_out, int out_size, void* d_ws, size_t ws_size,
                              hipStream_t stream) {
    const float* sp    = (const float*)d_in[0];
    const float* w_in  = (const float*)d_in[1];
    const float* w0    = (const float*)d_in[2];
    const float* bnp0  = (const float*)d_in[3];
    const float* w0a   = (const float*)d_in[4];
    const float* bnp0a = (const float*)d_in[5];
    const float* w0b   = (const float*)d_in[6];
    const float* bnp0b = (const float*)d_in[7];
    const float* w1    = (const float*)d_in[8];
    const float* bnp1  = (const float*)d_in[9];
    const float* w1a   = (const float*)d_in[10];
    const float* bnp1a = (const float*)d_in[11];
    const float* w1b   = (const float*)d_in[12];
    const float* bnp1b = (const float*)d_in[13];
    const float* ct0w  = (const float*)d_in[14];
    const float* ct0b  = (const float*)d_in[15];
    const float* bnt0  = (const float*)d_in[16];
    const float* ct1w  = (const float*)d_in[17];
    const float* ct1b  = (const float*)d_in[18];
    const float* bnt1  = (const float*)d_in[19];
    const int* coords0 = (const int*)d_in[20];
    const int* coords1 = (const int*)d_in[21];
    const int* g0 = (const int*)d_in[22];
    const int* s0 = (const int*)d_in[23];
    const int* ga = (const int*)d_in[24];
    const int* sa = (const int*)d_in[25];
    const int* g1 = (const int*)d_in[26];
    const int* s1 = (const int*)d_in[27];
    const int* gb = (const int*)d_in[28];
    const int* sb = (const int*)d_in[29];
    float* out = (float*)d_out;

    // -------- workspace carve --------
    __half* fInH = (__half*)d_ws;
    __half* R1h  = fInH + 640000;
    __half* R2h  = R1h + 22528000;
    __half* wt0  = R2h + 22528000;
    __half* wt0a = wt0  + 27648;
    __half* wt0b = wt0a + 27648;
    __half* wt1  = wt0b + 27648;          // [27][64][32]
    __half* wt1a = wt1  + 55296;          // [27][64][64]
    __half* wt1b = wt1a + 110592;
    __half* wtT0 = wt1b + 110592;         // [64][320]
    __half* wtT1 = wtT0 + 20480;          // [4][64][320]
    int*   nbrT = (int*)(wtT1 + 81920);
    int*   v2r0 = nbrT;                          // 2,816,000 ints
    int*   v2r1 = nbrT + 2816000;                //   352,000 ints

    // 0) weight conversion
    cvt_w<<<(27*32*32 + 255) / 256, 256, 0, stream>>>(w0,  wt0,  32, 32);
    cvt_w<<<(27*32*32 + 255) / 256, 256, 0, stream>>>(w0a, wt0a, 32, 32);
    cvt_w<<<(27*32*32 + 255) / 256, 256, 0, stream>>>(w0b, wt0b, 32, 32);
    cvt_w<<<(27*32*64 + 255) / 256, 256, 0, stream>>>(w1,  wt1,  32, 64);
    cvt_w<<<(27*64*64 + 255) / 256, 256, 0, stream>>>(w1a, wt1a, 64, 64);
    cvt_w<<<(27*64*64 + 255) / 256, 256, 0, stream>>>(w1b, wt1b, 64, 64);
    cvt_ct0<<<(64*320 + 255) / 256, 256, 0, stream>>>(ct0w, wtT0);
    cvt_ct1<<<(4*64*320 + 255) / 256, 256, 0, stream>>>(ct1w, wtT1);

    // 1) input channel lift (f16 rows out)
    gemm_in<<<(N_PTS_IN * 8 + 255) / 256, 256, 0, stream>>>(sp, w_in, fInH);

    // 2) conv0 (stride-1 spconv, 32->32): fInH -> R1h
    hipMemsetAsync(nbrT, 0xFF, (size_t)CAP0C * 27 * 4, stream);
    build_nbr<<<(27 * N_PTS_IN + 255) / 256, 256, 0, stream>>>(g0, s0, nbrT, N_PTS_IN, CAP0C);
    spconv_reg<32, 32><<<(CAP0C + 127) / 128, 256, 0, stream>>>(fInH, wt0, bnp0, nbrT, R1h, CAP0C);

    // 3) subm a/b (32->32), shared rulebook: R1h -> R2h -> R1h
    hipMemsetAsync(nbrT, 0xFF, (size_t)CAP0C * 27 * 4, stream);
    build_nbr<<<(27 * CAP0C + 255) / 256, 256, 0, stream>>>(ga, sa, nbrT, CAP0C, CAP0C);
    spconv_reg<32, 32><<<(CAP0C + 127) / 128, 256, 0, stream>>>(R1h, wt0a, bnp0a, nbrT, R2h, CAP0C);
    spconv_reg<32, 32><<<(CAP0C + 127) / 128, 256, 0, stream>>>(R2h, wt0b, bnp0b, nbrT, R1h, CAP0C);

    // 4) BEV head 0 (reads R1h) -> out channels [0,64)
    hipMemsetAsync(v2r0, 0xFF, (size_t)2816000 * 4, stream);
    build_vox<<<(CAP0C + 255) / 256, 256, 0, stream>>>(coords0, v2r0, CAP0C, ZD, YD, XD);
    bev0_mfma<<<YD * 22, 256, 0, stream>>>(R1h, wtT0, ct0b, bnt0, v2r0, out);

    // 5) conv1 (stride-2 spconv, 32->64): R1h -> R2h
    hipMemsetAsync(nbrT, 0xFF, (size_t)CAP1C * 27 * 4, stream);
    build_nbr<<<(27 * CAP0C + 255) / 256, 256, 0, stream>>>(g1, s1, nbrT, CAP0C, CAP1C);
    spconv_reg<32, 64><<<(CAP1C + 127) / 128, 256, 0, stream>>>(R1h, wt1, bnp1, nbrT, R2h, CAP1C);

    // 6) subm 1a/1b (64->64), shared rulebook: R2h -> R1h -> R2h
    hipMemsetAsync(nbrT, 0xFF, (size_t)CAP1C * 27 * 4, stream);
    build_nbr<<<(27 * CAP1C + 255) / 256, 256, 0, stream>>>(gb, sb, nbrT, CAP1C, CAP1C);
    spconv_reg<64, 64><<<(CAP1C + 127) / 128, 256, 0, stream>>>(R2h, wt1a, bnp1a, nbrT, R1h, CAP1C);
    spconv_reg<64, 64><<<(CAP1C + 127) / 128, 256, 0, stream>>>(R1h, wt1b, bnp1b, nbrT, R2h, CAP1C);

    // 7) BEV head 1 (reads R2h) -> out channels [64,128)
    hipMemsetAsync(v2r1, 0xFF, (size_t)352000 * 4, stream);
    build_vox<<<(CAP1C + 255) / 256, 256, 0, stream>>>(coords1, v2r1, CAP1C, Z1D, Y1D, X1D);
    bev1_mfma<<<Y1D * 11, 256, 0, stream>>>(R2h, wtT1, ct1b, bnt1, v2r1, out + (size_t)64 * HWOUT);
}

// Round 5
// 1183.156 us; speedup vs baseline: 1.4711x; 1.4711x over previous
//
#include <hip/hip_runtime.h>
#include <hip/hip_bf16.h>
#include <hip/hip_fp16.h>

// Problem constants
#define N_PTS_IN   20000
#define CAP0C      540000
#define CAP1C      352000
#define ZD 10
#define YD 200
#define XD 704
#define Z1D 5
#define Y1D 100
#define X1D 352
#define HWOUT (YD*XD)   // 140800

typedef _Float16 f16x8 __attribute__((ext_vector_type(8)));
typedef float    f32x4 __attribute__((ext_vector_type(4)));

// ---------------------------------------------------------------------------
// f_in = sp_feats @ w_in   (20000x64 @ 64x32), f16 output rows
__global__ __launch_bounds__(256) void gemm_in(const float* __restrict__ sp,
                                               const float* __restrict__ w,
                                               __half* __restrict__ fout) {
    int tid = blockIdx.x * 256 + threadIdx.x;
    int row = tid >> 3;
    int c4  = (tid & 7) * 4;
    if (row >= N_PTS_IN) return;
    float4 acc = {0.f, 0.f, 0.f, 0.f};
    const float* sr = sp + (size_t)row * 64;
#pragma unroll
    for (int ci = 0; ci < 64; ci += 4) {
        float4 fv = *(const float4*)(sr + ci);
        const float* wp = w + ci * 32 + c4;
        float4 w0 = *(const float4*)(wp);
        float4 w1 = *(const float4*)(wp + 32);
        float4 w2 = *(const float4*)(wp + 64);
        float4 w3 = *(const float4*)(wp + 96);
        acc.x += fv.x*w0.x + fv.y*w1.x + fv.z*w2.x + fv.w*w3.x;
        acc.y += fv.x*w0.y + fv.y*w1.y + fv.z*w2.y + fv.w*w3.y;
        acc.z += fv.x*w0.z + fv.y*w1.z + fv.z*w2.z + fv.w*w3.z;
        acc.w += fv.x*w0.w + fv.y*w1.w + fv.z*w2.w + fv.w*w3.w;
    }
    __half* fo = fout + (size_t)row * 32 + c4;
    fo[0] = __float2half(acc.x);
    fo[1] = __float2half(acc.y);
    fo[2] = __float2half(acc.z);
    fo[3] = __float2half(acc.w);
}

// ---------------------------------------------------------------------------
// Weight convert+transpose: src f32 [27][CIN][COUT] -> dst f16 [27][COUT][CIN]
__global__ __launch_bounds__(256) void cvt_w(const float* __restrict__ src,
                                             __half* __restrict__ dst,
                                             int CIN, int COUT) {
    int i = blockIdx.x * 256 + threadIdx.x;
    if (i >= 27 * CIN * COUT) return;
    int ci = i % CIN;
    int t  = i / CIN;
    int co = t % COUT;
    int k  = t / COUT;
    dst[i] = __float2half(src[((size_t)k * CIN + ci) * COUT + co]);
}

// ct0_w f32 [320][64] (ci=c*10+z) -> f16 [co][zc=z*32+c]
__global__ __launch_bounds__(256) void cvt_ct0(const float* __restrict__ src,
                                               __half* __restrict__ dst) {
    int i = blockIdx.x * 256 + threadIdx.x;
    if (i >= 64 * 320) return;
    int zc = i % 320, co = i / 320;
    int z = zc >> 5, c = zc & 31;
    dst[i] = __float2half(src[(c * 10 + z) * 64 + co]);
}

// ct1_w f32 [320][64][2][2] (ci=c*5+z) -> f16 [kq][co][zc=z*64+c]
__global__ __launch_bounds__(256) void cvt_ct1(const float* __restrict__ src,
                                               __half* __restrict__ dst) {
    int i = blockIdx.x * 256 + threadIdx.x;
    if (i >= 4 * 64 * 320) return;
    int zc = i % 320;
    int t  = i / 320;
    int co = t & 63;
    int kq = t >> 6;
    int z = zc >> 6, c = zc & 63;
    dst[i] = __float2half(src[((c * 5 + z) * 64 + co) * 4 + kq]);
}

// ---------------------------------------------------------------------------
// Rulebook inversion, TRANSPOSED: nbrT[k*cap + s] = g
__global__ __launch_bounds__(256) void build_nbr(const int* __restrict__ g,
                                                 const int* __restrict__ s,
                                                 int* __restrict__ nbrT,
                                                 int P, int cap) {
    int i = blockIdx.x * 256 + threadIdx.x;
    if (i >= 27 * P) return;
    int k = i / P, p = i - k * P;
    int sv = s[(size_t)k * P + p];
    if (sv >= cap) return;              // dummy pair
    nbrT[(size_t)k * cap + sv] = g[(size_t)k * P + p];
}

// voxel -> sparse-row index (pad coords have z == Zdim, dropped like JAX OOB)
__global__ __launch_bounds__(256) void build_vox(const int* __restrict__ coords,
                                                 int* __restrict__ v2r,
                                                 int cap, int Zdim, int Ydim, int Xdim) {
    int r = blockIdx.x * 256 + threadIdx.x;
    if (r >= cap) return;
    int b = coords[4*r], z = coords[4*r+1], y = coords[4*r+2], x = coords[4*r+3];
    if (z >= Zdim) return;
    v2r[(((size_t)b * Zdim + z) * Ydim + y) * Xdim + x] = r;
}

// ---------------------------------------------------------------------------
// Implicit-GEMM sparse conv via f16 MFMA 16x16x32, + BN + ReLU.
// v11: weights via LDS (TA-pipe relief).
// R4 cross-round arithmetic: per-wave-iter cost ~3.8-5.2 Kcy in ALL versions
// and it SCALES with waves/CU -> a shared per-CU pipe is saturated: the
// vector-memory address path (1 cy per cache line touched; divergent loads
// = 16-32 lines per inst). ~60% of the line budget was every wave re-reading
// the SAME 8KB weight tile from global per k (L2-hit, invisible in FETCH).
// Fix: block-cooperative double-buffered weight staging in LDS:
//   - per k: issue gathers (regs) -> issue per-thread 8-32B stage load (regs)
//     -> ds_read B (swizzled, conflict-free) -> MFMA -> ds_write stage ->
//     one __syncthreads. T14-style issue-early/write-late: stage latency
//     hides under gather-wait + MFMA.
//   - weight TA cost: 32 lines/BLOCK/k instead of 128-256 lines/WAVE/k.
//   - idx loads issued FIRST (oldest) -> retired by the time the barrier's
//     vmcnt(0) drain hits; depth-2 pipeline unchanged.
// Gathers stay direct-to-register (v10), f32x4 acc (32 AGPR), epilogue LDS
// unioned with the weight buffers.
template <int CIN, int COUT>
__global__ __launch_bounds__(256) void spconv_reg(const __half* __restrict__ f,
                                                  const __half* __restrict__ wt,
                                                  const float* __restrict__ bnp,
                                                  const int* __restrict__ nbrT,
                                                  __half* __restrict__ fout,
                                                  int ncap) {
    constexpr int NT = COUT / 16;       // 16-col output tiles
    constexpr int KT = CIN / 32;        // K=32 MFMA steps per k-offset
    constexpr int NCHUNK = CIN / 8;     // 16B chunks per weight row
    constexpr int MASK = NCHUNK - 1;
    constexpr int LCH  = (NCHUNK == 8) ? 3 : 2;
    constexpr int TILE_H = COUT * CIN;  // halves per weight tile
    constexpr int TB = TILE_H * 2 / 256; // stage bytes per thread (8/16/32)
    constexpr int OST_H = 4 * 32 * COUT;
    constexpr int SH_H = (2 * TILE_H > OST_H) ? 2 * TILE_H : OST_H;
    __shared__ __align__(16) __half S[SH_H];

    int tid = threadIdx.x;
    int wv = tid >> 6, lane = tid & 63;
    int quad = lane >> 4, l16 = lane & 15;

    // bijective XCD-aware block swizzle (m204 form)
    int nwg = gridDim.x;
    int q = nwg >> 3, rm = nwg & 7;
    int xcd = blockIdx.x & 7, off = blockIdx.x >> 3;
    int sb = (xcd < rm ? xcd * (q + 1) : rm * (q + 1) + (xcd - rm) * q) + off;

    int m0 = sb * 128 + wv * 32;       // wave's first output row
    int r0 = m0 + l16;                 // this lane's row for m=0
    int r1 = m0 + 16 + l16;            // this lane's row for m=1
    bool ok0 = r0 < ncap, ok1 = r1 < ncap;

    f32x4 acc[2][NT] = {};

    // index pipeline depth 2
    int gC0 = ok0 ? nbrT[r0] : -1;
    int gC1 = ok1 ? nbrT[r1] : -1;
    int gN0 = ok0 ? nbrT[(size_t)ncap + r0] : -1;
    int gN1 = ok1 ? nbrT[(size_t)ncap + r1] : -1;
    bool ever = false;

    // ---- prologue: stage weight tile k=0 into buffer 0 ----
    {
        const char* src = (const char*)(wt) + tid * TB;
        if constexpr (TB == 32) {
            uint4 w0 = *(const uint4*)src;
            uint4 w1 = *(const uint4*)(src + 16);
            int p0 = tid * 2;
#pragma unroll
            for (int j = 0; j < 2; ++j) {
                int p = p0 + j;
                int row = p >> LCH, c = p & MASK;
                *(uint4*)(S + (row * NCHUNK + (c ^ (row & MASK))) * 8) = (j ? w1 : w0);
            }
        } else if constexpr (TB == 16) {
            uint4 w0 = *(const uint4*)src;
            int p = tid;
            int row = p >> LCH, c = p & MASK;
            *(uint4*)(S + (row * NCHUNK + (c ^ (row & MASK))) * 8) = w0;
        } else {
            uint2 w0 = *(const uint2*)src;
            int p = tid >> 1, half = tid & 1;
            int row = p >> LCH, c = p & MASK;
            *(uint2*)(S + (row * NCHUNK + (c ^ (row & MASK))) * 8 + half * 4) = w0;
        }
    }
    __syncthreads();

#pragma unroll 1
    for (int k = 0; k < 27; ++k) {
        // (1) idx k+2 (oldest in-flight: retired before barrier drain)
        int gNN0 = -1, gNN1 = -1;
        if (k + 2 < 27) {
            if (ok0) gNN0 = nbrT[(size_t)(k + 2) * ncap + r0];
            if (ok1) gNN1 = nbrT[(size_t)(k + 2) * ncap + r1];
        }
        // (2) gathers k -> regs
        bool anyC = __ballot((gC0 >= 0) || (gC1 >= 0)) != 0ull;
        f16x8 a0[KT], a1[KT];
        if (anyC) {
            const __half* p0 = f + (size_t)((gC0 < 0) ? 0 : gC0) * CIN + quad * 8;
            const __half* p1 = f + (size_t)((gC1 < 0) ? 0 : gC1) * CIN + quad * 8;
#pragma unroll
            for (int kt = 0; kt < KT; ++kt) {
                uint4 u0 = {0u,0u,0u,0u}, u1 = {0u,0u,0u,0u};
                if (gC0 >= 0) u0 = *(const uint4*)(p0 + kt * 32);
                if (gC1 >= 0) u1 = *(const uint4*)(p1 + kt * 32);
                a0[kt] = *(f16x8*)&u0;
                a1[kt] = *(f16x8*)&u1;
            }
        }
        // (3) stage loads for k+1 -> regs (youngest: stays in flight
        //     across the MFMA's gather-wait)
        bool doStage = (k + 1 < 27);
        uint4 w0{}, w1{}; uint2 w2{};
        if (doStage) {
            const char* src = (const char*)(wt + (size_t)(k + 1) * TILE_H) + tid * TB;
            if constexpr (TB == 32)      { w0 = *(const uint4*)src; w1 = *(const uint4*)(src + 16); }
            else if constexpr (TB == 16) { w0 = *(const uint4*)src; }
            else                         { w2 = *(const uint2*)src; }
        }
        // (4) ds_read B + (5) MFMA
        if (anyC) {
            ever = true;
            const __half* Wb = S + (k & 1) * TILE_H;
#pragma unroll
            for (int kt = 0; kt < KT; ++kt) {
#pragma unroll
                for (int nt = 0; nt < NT; ++nt) {
                    int row = nt * 16 + l16;
                    int c   = kt * 4 + quad;
                    f16x8 b = *(const f16x8*)(Wb + (row * NCHUNK + (c ^ (row & MASK))) * 8);
                    acc[0][nt] = __builtin_amdgcn_mfma_f32_16x16x32_f16(a0[kt], b, acc[0][nt], 0, 0, 0);
                    acc[1][nt] = __builtin_amdgcn_mfma_f32_16x16x32_f16(a1[kt], b, acc[1][nt], 0, 0, 0);
                }
            }
        }
        // (6) ds_write staging into the other buffer
        if (doStage) {
            __half* dst = S + ((k + 1) & 1) * TILE_H;
            if constexpr (TB == 32) {
                int p0 = tid * 2;
#pragma unroll
                for (int j = 0; j < 2; ++j) {
                    int p = p0 + j;
                    int row = p >> LCH, c = p & MASK;
                    *(uint4*)(dst + (row * NCHUNK + (c ^ (row & MASK))) * 8) = (j ? w1 : w0);
                }
            } else if constexpr (TB == 16) {
                int p = tid;
                int row = p >> LCH, c = p & MASK;
                *(uint4*)(dst + (row * NCHUNK + (c ^ (row & MASK))) * 8) = w0;
            } else {
                int p = tid >> 1, half = tid & 1;
                int row = p >> LCH, c = p & MASK;
                *(uint2*)(dst + (row * NCHUNK + (c ^ (row & MASK))) * 8 + half * 4) = w2;
            }
        }
        __syncthreads();
        gC0 = gN0; gC1 = gN1; gN0 = gNN0; gN1 = gNN1;
    }

    // epilogue: BN + ReLU -> wave-private LDS (weight bufs dead) -> store.
    if (!ever) return;
    __half* O = S + wv * (32 * COUT);
#pragma unroll
    for (int nt = 0; nt < NT; ++nt) {
        int co = nt * 16 + l16;
        float g = bnp[co], b = bnp[COUT + co];
        float mn = bnp[2*COUT + co], vv = bnp[3*COUT + co];
        float s  = g * rsqrtf(vv + 1e-5f);
        float sh = b - mn * s;
#pragma unroll
        for (int m = 0; m < 2; ++m)
#pragma unroll
            for (int r_ = 0; r_ < 4; ++r_) {
                int row = m * 16 + quad * 4 + r_;
                O[row * COUT + co] = __float2half(fmaxf(acc[m][nt][r_] * s + sh, 0.f));
            }
    }
    constexpr int OCH = COUT / 8;              // 16B chunks per out row
#pragma unroll
    for (int j = 0; j < 32 * OCH / 64; ++j) {
        int idx = j * 64 + lane;
        int r = idx / OCH, c = idx % OCH;
        if (m0 + r < ncap)
            *(uint4*)(fout + (size_t)(m0 + r) * COUT + c * 8) =
                *(const uint4*)(O + r * COUT + c * 8);
    }
}

// ---------------------------------------------------------------------------
// BEV head 0: fused gather + GEMM [64rows x 320] @ [320 x 64] via f16 MFMA,
// + BN + ReLU + 2-agent attention + coalesced store.
__global__ __launch_bounds__(256) void bev0_mfma(const __half* __restrict__ f0,
                                                 const __half* __restrict__ wtT,  // [64][320] zc=z*32+c
                                                 const float* __restrict__ bias,
                                                 const float* __restrict__ bnp,
                                                 const int* __restrict__ v2r,
                                                 float* __restrict__ out) {
    constexpr int AST = 328;
    __shared__ __align__(16) __half Al[64 * AST];   // 41,984 B
    __shared__ float Cl[64][65];                     // wave-private rows
    __shared__ float Ot[64][33];
    int tid = threadIdx.x;
    int y = blockIdx.x / 22, x0 = (blockIdx.x % 22) * 32;
    int wv = tid >> 6, lane = tid & 63;
    int quad = lane >> 4, l16 = lane & 15;

    for (int it = 0; it < 3; ++it) {
        int task = it * 256 + tid;
        if (task < 640) {
            int row = task & 63, z = task >> 6;
            int b = row & 1, p = row >> 1;
            int r = v2r[((b * ZD + z) * YD + y) * XD + x0 + p];
            uint4 v0 = {0,0,0,0}, v1 = {0,0,0,0}, v2 = {0,0,0,0}, v3 = {0,0,0,0};
            if (r >= 0) {
                const uint4* src = (const uint4*)(f0 + (size_t)r * 32);
                v0 = src[0]; v1 = src[1]; v2 = src[2]; v3 = src[3];
            }
            uint4* dst = (uint4*)(Al + row * AST + z * 32);
            dst[0] = v0; dst[1] = v1; dst[2] = v2; dst[3] = v3;
        }
    }
    __syncthreads();

    f32x4 acc[4] = {};
#pragma unroll
    for (int ks = 0; ks < 10; ++ks) {
        f16x8 a = *(const f16x8*)(Al + (wv * 16 + l16) * AST + ks * 32 + quad * 8);
#pragma unroll
        for (int nt = 0; nt < 4; ++nt) {
            f16x8 bfr = *(const f16x8*)(wtT + (size_t)(nt * 16 + l16) * 320 + ks * 32 + quad * 8);
            acc[nt] = __builtin_amdgcn_mfma_f32_16x16x32_f16(a, bfr, acc[nt], 0, 0, 0);
        }
    }
#pragma unroll
    for (int nt = 0; nt < 4; ++nt) {
        int co = nt * 16 + l16;
        float s  = bnp[co] * rsqrtf(bnp[192 + co] + 1e-5f);
        float sh = (bias[co] - bnp[128 + co]) * s + bnp[64 + co];
#pragma unroll
        for (int r_ = 0; r_ < 4; ++r_)
            Cl[wv * 16 + quad * 4 + r_][co] = fmaxf(acc[nt][r_] * s + sh, 0.f);
    }
#pragma unroll
    for (int pi = 0; pi < 8; ++pi) {
        int p = wv * 8 + pi;
        float x0v = Cl[2 * p][lane], x1v = Cl[2 * p + 1][lane];
        float s00 = x0v * x0v, s01 = x0v * x1v;
#pragma unroll
        for (int o = 32; o > 0; o >>= 1) {
            s00 += __shfl_xor(s00, o);
            s01 += __shfl_xor(s01, o);
        }
        float a0 = s00 * 0.125f, a1 = s01 * 0.125f;
        float mx = fmaxf(a0, a1);
        float e0 = expf(a0 - mx), e1 = expf(a1 - mx);
        float inv = 1.f / (e0 + e1);
        Ot[lane][p] = (e0 * x0v + e1 * x1v) * inv;
    }
    __syncthreads();
#pragma unroll
    for (int i = 0; i < 8; ++i) {
        int idx = i * 256 + tid;
        int co = idx >> 5, px = idx & 31;
        out[(size_t)co * HWOUT + (size_t)y * XD + x0 + px] = Ot[co][px];
    }
}

// ---------------------------------------------------------------------------
// BEV head 1: fused gather + 4x (GEMM [64x320]@[320x64]) for the 2x2 s2 convT
// kernel positions + BN + ReLU + attention + coalesced store.
__global__ __launch_bounds__(256) void bev1_mfma(const __half* __restrict__ f1,
                                                 const __half* __restrict__ wtT,  // [4][64][320] zc=z*64+c
                                                 const float* __restrict__ bias,
                                                 const float* __restrict__ bnp,
                                                 const int* __restrict__ v2r,
                                                 float* __restrict__ out) {
    constexpr int AST = 328;
    __shared__ __align__(16) __half Al[64 * AST];
    __shared__ float Cl[64][65];
    __shared__ float Ot[64][65];
    int tid = threadIdx.x;
    int iy = blockIdx.x / 11, j0 = (blockIdx.x % 11) * 32;
    int wv = tid >> 6, lane = tid & 63;
    int quad = lane >> 4, l16 = lane & 15;

    for (int it = 0; it < 3; ++it) {
        int task = it * 256 + tid;
        if (task < 640) {
            int row = task & 63, zh = task >> 6;   // 0..9
            int z = zh >> 1, hf = zh & 1;
            int b = row & 1, p = row >> 1;
            int r = v2r[((b * Z1D + z) * Y1D + iy) * X1D + j0 + p];
            uint4 v0 = {0,0,0,0}, v1 = {0,0,0,0}, v2 = {0,0,0,0}, v3 = {0,0,0,0};
            if (r >= 0) {
                const uint4* src = (const uint4*)(f1 + (size_t)r * 64 + hf * 32);
                v0 = src[0]; v1 = src[1]; v2 = src[2]; v3 = src[3];
            }
            uint4* dst = (uint4*)(Al + row * AST + z * 64 + hf * 32);
            dst[0] = v0; dst[1] = v1; dst[2] = v2; dst[3] = v3;
        }
    }
    __syncthreads();

#pragma unroll 1
    for (int ky = 0; ky < 2; ++ky) {
#pragma unroll 1
        for (int kx = 0; kx < 2; ++kx) {
            const __half* wk = wtT + (size_t)(ky * 2 + kx) * 64 * 320;
            f32x4 acc[4] = {};
#pragma unroll
            for (int ks = 0; ks < 10; ++ks) {
                f16x8 a = *(const f16x8*)(Al + (wv * 16 + l16) * AST + ks * 32 + quad * 8);
#pragma unroll
                for (int nt = 0; nt < 4; ++nt) {
                    f16x8 bfr = *(const f16x8*)(wk + (size_t)(nt * 16 + l16) * 320 + ks * 32 + quad * 8);
                    acc[nt] = __builtin_amdgcn_mfma_f32_16x16x32_f16(a, bfr, acc[nt], 0, 0, 0);
                }
            }
#pragma unroll
            for (int nt = 0; nt < 4; ++nt) {
                int co = nt * 16 + l16;
                float s  = bnp[co] * rsqrtf(bnp[192 + co] + 1e-5f);
                float sh = (bias[co] - bnp[128 + co]) * s + bnp[64 + co];
#pragma unroll
                for (int r_ = 0; r_ < 4; ++r_)
                    Cl[wv * 16 + quad * 4 + r_][co] = fmaxf(acc[nt][r_] * s + sh, 0.f);
            }
#pragma unroll
            for (int pi = 0; pi < 8; ++pi) {
                int p = wv * 8 + pi;
                float x0v = Cl[2 * p][lane], x1v = Cl[2 * p + 1][lane];
                float s00 = x0v * x0v, s01 = x0v * x1v;
#pragma unroll
                for (int o = 32; o > 0; o >>= 1) {
                    s00 += __shfl_xor(s00, o);
                    s01 += __shfl_xor(s01, o);
                }
                float a0 = s00 * 0.125f, a1 = s01 * 0.125f;
                float mx = fmaxf(a0, a1);
                float e0 = expf(a0 - mx), e1 = expf(a1 - mx);
                float inv = 1.f / (e0 + e1);
                Ot[lane][2 * p + kx] = (e0 * x0v + e1 * x1v) * inv;
            }
        }
        __syncthreads();
        int yo = 2 * iy + ky;
#pragma unroll
        for (int i = 0; i < 16; ++i) {
            int idx = i * 256 + tid;
            int co = idx >> 6, xx = idx & 63;
            out[(size_t)co * HWOUT + (size_t)yo * XD + 2 * j0 + xx] = Ot[co][xx];
        }
        __syncthreads();
    }
}

// ---------------------------------------------------------------------------
extern "C" void kernel_launch(void* const* d_in, const int* in_sizes, int n_in,
                              void* d_out, int out_size, void* d_ws, size_t ws_size,
                              hipStream_t stream) {
    const float* sp    = (const float*)d_in[0];
    const float* w_in  = (const float*)d_in[1];
    const float* w0    = (const float*)d_in[2];
    const float* bnp0  = (const float*)d_in[3];
    const float* w0a   = (const float*)d_in[4];
    const float* bnp0a = (const float*)d_in[5];
    const float* w0b   = (const float*)d_in[6];
    const float* bnp0b = (const float*)d_in[7];
    const float* w1    = (const float*)d_in[8];
    const float* bnp1  = (const float*)d_in[9];
    const float* w1a   = (const float*)d_in[10];
    const float* bnp1a = (const float*)d_in[11];
    const float* w1b   = (const float*)d_in[12];
    const float* bnp1b = (const float*)d_in[13];
    const float* ct0w  = (const float*)d_in[14];
    const float* ct0b  = (const float*)d_in[15];
    const float* bnt0  = (const float*)d_in[16];
    const float* ct1w  = (const float*)d_in[17];
    const float* ct1b  = (const float*)d_in[18];
    const float* bnt1  = (const float*)d_in[19];
    const int* coords0 = (const int*)d_in[20];
    const int* coords1 = (const int*)d_in[21];
    const int* g0 = (const int*)d_in[22];
    const int* s0 = (const int*)d_in[23];
    const int* ga = (const int*)d_in[24];
    const int* sa = (const int*)d_in[25];
    const int* g1 = (const int*)d_in[26];
    const int* s1 = (const int*)d_in[27];
    const int* gb = (const int*)d_in[28];
    const int* sb = (const int*)d_in[29];
    float* out = (float*)d_out;

    // -------- workspace carve --------
    __half* fInH = (__half*)d_ws;
    __half* R1h  = fInH + 640000;
    __half* R2h  = R1h + 22528000;
    __half* wt0  = R2h + 22528000;
    __half* wt0a = wt0  + 27648;
    __half* wt0b = wt0a + 27648;
    __half* wt1  = wt0b + 27648;          // [27][64][32]
    __half* wt1a = wt1  + 55296;          // [27][64][64]
    __half* wt1b = wt1a + 110592;
    __half* wtT0 = wt1b + 110592;         // [64][320]
    __half* wtT1 = wtT0 + 20480;          // [4][64][320]
    int*   nbrT = (int*)(wtT1 + 81920);
    int*   v2r0 = nbrT;                          // 2,816,000 ints
    int*   v2r1 = nbrT + 2816000;                //   352,000 ints

    // 0) weight conversion
    cvt_w<<<(27*32*32 + 255) / 256, 256, 0, stream>>>(w0,  wt0,  32, 32);
    cvt_w<<<(27*32*32 + 255) / 256, 256, 0, stream>>>(w0a, wt0a, 32, 32);
    cvt_w<<<(27*32*32 + 255) / 256, 256, 0, stream>>>(w0b, wt0b, 32, 32);
    cvt_w<<<(27*32*64 + 255) / 256, 256, 0, stream>>>(w1,  wt1,  32, 64);
    cvt_w<<<(27*64*64 + 255) / 256, 256, 0, stream>>>(w1a, wt1a, 64, 64);
    cvt_w<<<(27*64*64 + 255) / 256, 256, 0, stream>>>(w1b, wt1b, 64, 64);
    cvt_ct0<<<(64*320 + 255) / 256, 256, 0, stream>>>(ct0w, wtT0);
    cvt_ct1<<<(4*64*320 + 255) / 256, 256, 0, stream>>>(ct1w, wtT1);

    // 1) input channel lift (f16 rows out)
    gemm_in<<<(N_PTS_IN * 8 + 255) / 256, 256, 0, stream>>>(sp, w_in, fInH);

    // 2) conv0 (stride-1 spconv, 32->32): fInH -> R1h
    hipMemsetAsync(nbrT, 0xFF, (size_t)CAP0C * 27 * 4, stream);
    build_nbr<<<(27 * N_PTS_IN + 255) / 256, 256, 0, stream>>>(g0, s0, nbrT, N_PTS_IN, CAP0C);
    spconv_reg<32, 32><<<(CAP0C + 127) / 128, 256, 0, stream>>>(fInH, wt0, bnp0, nbrT, R1h, CAP0C);

    // 3) subm a/b (32->32), shared rulebook: R1h -> R2h -> R1h
    hipMemsetAsync(nbrT, 0xFF, (size_t)CAP0C * 27 * 4, stream);
    build_nbr<<<(27 * CAP0C + 255) / 256, 256, 0, stream>>>(ga, sa, nbrT, CAP0C, CAP0C);
    spconv_reg<32, 32><<<(CAP0C + 127) / 128, 256, 0, stream>>>(R1h, wt0a, bnp0a, nbrT, R2h, CAP0C);
    spconv_reg<32, 32><<<(CAP0C + 127) / 128, 256, 0, stream>>>(R2h, wt0b, bnp0b, nbrT, R1h, CAP0C);

    // 4) BEV head 0 (reads R1h) -> out channels [0,64)
    hipMemsetAsync(v2r0, 0xFF, (size_t)2816000 * 4, stream);
    build_vox<<<(CAP0C + 255) / 256, 256, 0, stream>>>(coords0, v2r0, CAP0C, ZD, YD, XD);
    bev0_mfma<<<YD * 22, 256, 0, stream>>>(R1h, wtT0, ct0b, bnt0, v2r0, out);

    // 5) conv1 (stride-2 spconv, 32->64): R1h -> R2h
    hipMemsetAsync(nbrT, 0xFF, (size_t)CAP1C * 27 * 4, stream);
    build_nbr<<<(27 * CAP0C + 255) / 256, 256, 0, stream>>>(g1, s1, nbrT, CAP0C, CAP1C);
    spconv_reg<32, 64><<<(CAP1C + 127) / 128, 256, 0, stream>>>(R1h, wt1, bnp1, nbrT, R2h, CAP1C);

    // 6) subm 1a/1b (64->64), shared rulebook: R2h -> R1h -> R2h
    hipMemsetAsync(nbrT, 0xFF, (size_t)CAP1C * 27 * 4, stream);
    build_nbr<<<(27 * CAP1C + 255) / 256, 256, 0, stream>>>(gb, sb, nbrT, CAP1C, CAP1C);
    spconv_reg<64, 64><<<(CAP1C + 127) / 128, 256, 0, stream>>>(R2h, wt1a, bnp1a, nbrT, R1h, CAP1C);
    spconv_reg<64, 64><<<(CAP1C + 127) / 128, 256, 0, stream>>>(R1h, wt1b, bnp1b, nbrT, R2h, CAP1C);

    // 7) BEV head 1 (reads R2h) -> out channels [64,128)
    hipMemsetAsync(v2r1, 0xFF, (size_t)352000 * 4, stream);
    build_vox<<<(CAP1C + 255) / 256, 256, 0, stream>>>(coords1, v2r1, CAP1C, Z1D, Y1D, X1D);
    bev1_mfma<<<Y1D * 11, 256, 0, stream>>>(R2h, wtT1, ct1b, bnt1, v2r1, out + (size_t)64 * HWOUT);
}